// Round 1
// baseline (747.684 us; speedup 1.0000x reference)
//
#include <hip/hip_runtime.h>

#define N_SRC 50000
#define N_DST 50000
#define N_EDGES 600000
#define IN_FEAT 128
#define OUT_FEAT 128

// ---------------------------------------------------------------------------
// Kernel 1: scatter-add edge messages into neigh_sum + degree.
// 256 threads/block = 4 edge-groups of 64 lanes; each lane handles 2 feats
// via a coalesced float2 load of the source row (512 B per edge row).
// ---------------------------------------------------------------------------
__global__ __launch_bounds__(256) void scatter_kernel(
    const float* __restrict__ h_s, const int* __restrict__ src,
    const int* __restrict__ dst, float* __restrict__ neigh_sum,
    float* __restrict__ deg)
{
    int tid  = threadIdx.x;
    int egrp = tid >> 6;      // 0..3
    int lane = tid & 63;      // 0..63
    int e = blockIdx.x * 4 + egrp;
    if (e >= N_EDGES) return;
    int s = src[e];
    int d = dst[e];
    float2 v = ((const float2*)(h_s + (size_t)s * IN_FEAT))[lane];
    float* drow = neigh_sum + (size_t)d * IN_FEAT + lane * 2;
    atomicAdd(drow + 0, v.x);
    atomicAdd(drow + 1, v.y);
    if (lane == 0) atomicAdd(deg + d, 1.0f);
}

// ---------------------------------------------------------------------------
// Kernel 2: fused mean + concat + linear.
// out[i][j] = b[j] + dot(h_d[i], W[j][0:128]) + inv_deg[i]*dot(neigh[i], W[j][128:256])
// Block tile: 64 rows x 128 cols, 256 threads, each thread 8 rows x 4 cols.
// The neigh tile is pre-scaled by inv_deg while staging into LDS, so a single
// accumulator set covers both K-halves (two sequential stages reuse one LDS
// buffer: 64x132 floats = 33.8 KB).
// ---------------------------------------------------------------------------
__global__ __launch_bounds__(256) void gemm_kernel(
    const float* __restrict__ h_d, const float* __restrict__ neigh_sum,
    const float* __restrict__ deg, const float* __restrict__ W,
    const float* __restrict__ b, float* __restrict__ out)
{
    __shared__ float As[64][132];   // pad 128->132 keeps float4 alignment

    int tid = threadIdx.x;
    int cg  = tid & 31;   // col group: cols 4*cg .. 4*cg+3
    int rg  = tid >> 5;   // row group: rows rg*8 .. rg*8+7
    int row0 = blockIdx.x * 64;

    float acc[8][4];
#pragma unroll
    for (int r = 0; r < 8; ++r)
#pragma unroll
        for (int c = 0; c < 4; ++c) acc[r][c] = 0.0f;

    for (int stage = 0; stage < 2; ++stage) {
        const float* srcmat = stage ? neigh_sum : h_d;
        __syncthreads();   // protect LDS reuse across stages
        // cooperative tile load: 64 rows x 32 float4
#pragma unroll
        for (int i = 0; i < 8; ++i) {
            int idx = tid + i * 256;
            int r   = idx >> 5;
            int c4  = idx & 31;
            int grow = row0 + r;
            float4 v = make_float4(0.f, 0.f, 0.f, 0.f);
            if (grow < N_DST) {
                v = ((const float4*)(srcmat + (size_t)grow * IN_FEAT))[c4];
                if (stage) {
                    float inv = 1.0f / fmaxf(deg[grow], 1.0f);
                    v.x *= inv; v.y *= inv; v.z *= inv; v.w *= inv;
                }
            }
            *(float4*)&As[r][c4 * 4] = v;
        }
        __syncthreads();

        const float* Wp = W + (size_t)(4 * cg) * (2 * IN_FEAT) + stage * IN_FEAT;
#pragma unroll 4
        for (int k4 = 0; k4 < 32; ++k4) {
            float4 w0 = *(const float4*)(Wp + 0 * 256 + k4 * 4);
            float4 w1 = *(const float4*)(Wp + 1 * 256 + k4 * 4);
            float4 w2 = *(const float4*)(Wp + 2 * 256 + k4 * 4);
            float4 w3 = *(const float4*)(Wp + 3 * 256 + k4 * 4);
#pragma unroll
            for (int r = 0; r < 8; ++r) {
                float4 a = *(const float4*)&As[rg * 8 + r][k4 * 4];
                acc[r][0] += a.x * w0.x + a.y * w0.y + a.z * w0.z + a.w * w0.w;
                acc[r][1] += a.x * w1.x + a.y * w1.y + a.z * w1.z + a.w * w1.w;
                acc[r][2] += a.x * w2.x + a.y * w2.y + a.z * w2.z + a.w * w2.w;
                acc[r][3] += a.x * w3.x + a.y * w3.y + a.z * w3.z + a.w * w3.w;
            }
        }
    }

    float4 bb = *(const float4*)(b + 4 * cg);
#pragma unroll
    for (int r = 0; r < 8; ++r) {
        int grow = row0 + rg * 8 + r;
        if (grow < N_DST) {
            float4 o;
            o.x = acc[r][0] + bb.x;
            o.y = acc[r][1] + bb.y;
            o.z = acc[r][2] + bb.z;
            o.w = acc[r][3] + bb.w;
            *(float4*)(out + (size_t)grow * OUT_FEAT + 4 * cg) = o;
        }
    }
}

extern "C" void kernel_launch(void* const* d_in, const int* in_sizes, int n_in,
                              void* d_out, int out_size, void* d_ws, size_t ws_size,
                              hipStream_t stream) {
    const float* h_s = (const float*)d_in[0];
    const float* h_d = (const float*)d_in[1];
    const int*   src = (const int*)d_in[2];
    const int*   dst = (const int*)d_in[3];
    const float* W   = (const float*)d_in[4];
    const float* b   = (const float*)d_in[5];
    float* out = (float*)d_out;

    float* neigh_sum = (float*)d_ws;                              // N_DST*IN_FEAT
    float* deg       = neigh_sum + (size_t)N_DST * IN_FEAT;       // N_DST

    size_t zero_bytes = ((size_t)N_DST * IN_FEAT + N_DST) * sizeof(float);
    hipMemsetAsync(d_ws, 0, zero_bytes, stream);

    scatter_kernel<<<(N_EDGES + 3) / 4, 256, 0, stream>>>(h_s, src, dst, neigh_sum, deg);

    gemm_kernel<<<(N_DST + 63) / 64, 256, 0, stream>>>(h_d, neigh_sum, deg, W, b, out);
}

// Round 2
// 472.514 us; speedup vs baseline: 1.5824x; 1.5824x over previous
//
#include <hip/hip_runtime.h>

#define N_SRC 50000
#define N_DST 50000
#define N_EDGES 600000
#define IN_FEAT 128
#define OUT_FEAT 128
#define SCAN_THREADS 1024
#define SCAN_CHUNK 49   // ceil(50000/1024)

// ---------------------------------------------------------------------------
// K1: degree histogram (int atomics, 600k total -> ~µs)
// ---------------------------------------------------------------------------
__global__ __launch_bounds__(256) void hist_kernel(
    const int* __restrict__ dst, int* __restrict__ deg)
{
    int e = blockIdx.x * 256 + threadIdx.x;
    if (e < N_EDGES) atomicAdd(&deg[dst[e]], 1);
}

// ---------------------------------------------------------------------------
// K2: single-block exclusive scan of degrees -> offsets[N_DST+1], cursor copy
// ---------------------------------------------------------------------------
__global__ __launch_bounds__(SCAN_THREADS) void scan_kernel(
    const int* __restrict__ deg, int* __restrict__ offsets,
    int* __restrict__ cursor)
{
    __shared__ int part[SCAN_THREADS];
    int t = threadIdx.x;
    int begin = t * SCAN_CHUNK;
    int end   = begin + SCAN_CHUNK;
    if (begin > N_DST) begin = N_DST;
    if (end   > N_DST) end   = N_DST;

    int s = 0;
    for (int i = begin; i < end; ++i) s += deg[i];
    part[t] = s;
    __syncthreads();
    // Hillis-Steele inclusive scan over the 1024 partials
    for (int o = 1; o < SCAN_THREADS; o <<= 1) {
        int v = (t >= o) ? part[t - o] : 0;
        __syncthreads();
        part[t] += v;
        __syncthreads();
    }
    int run = (t == 0) ? 0 : part[t - 1];
    for (int i = begin; i < end; ++i) {
        offsets[i] = run;
        cursor[i]  = run;
        run += deg[i];
    }
    if (t == SCAN_THREADS - 1) offsets[N_DST] = part[SCAN_THREADS - 1];
}

// ---------------------------------------------------------------------------
// K3: fill edge permutation: perm[slot] = src[e], slots grouped by dst row
// ---------------------------------------------------------------------------
__global__ __launch_bounds__(256) void fill_kernel(
    const int* __restrict__ src, const int* __restrict__ dst,
    int* __restrict__ cursor, int* __restrict__ perm)
{
    int e = blockIdx.x * 256 + threadIdx.x;
    if (e < N_EDGES) {
        int d = dst[e];
        int p = atomicAdd(&cursor[d], 1);
        perm[p] = src[e];
    }
}

// ---------------------------------------------------------------------------
// K4: fused gather-mean + concat + linear.
// out[i][j] = b[j] + dot(h_d[i], W[j][0:128])
//           + (1/max(deg,1)) * dot(sum_{e:dst=i} h_s[src[e]], W[j][128:256])
// Block tile 64 rows x 128 cols, 256 thr, each thread 8 rows x 4 cols.
// Stage 0: h_d tile loaded from global. Stage 1: neigh tile built in-LDS by
// gather-summing CSR edges: one wave per tile-row, 64 lanes x float2 = 128
// feats, 4-edge batching so loads issue back-to-back (ILP over ~500cy lat).
// ---------------------------------------------------------------------------
__global__ __launch_bounds__(256) void fused_gemm_kernel(
    const float* __restrict__ h_d, const float* __restrict__ h_s,
    const int* __restrict__ offsets, const int* __restrict__ perm,
    const float* __restrict__ W, const float* __restrict__ b,
    float* __restrict__ out)
{
    __shared__ float As[64][132];   // pad keeps float4 alignment, avoids pow2

    int tid  = threadIdx.x;
    int lane = tid & 63;
    int wave = tid >> 6;   // 0..3
    int cg   = tid & 31;   // cols 4*cg..4*cg+3
    int rg   = tid >> 5;   // rows rg*8..rg*8+7
    int row0 = blockIdx.x * 64;

    float acc[8][4];
#pragma unroll
    for (int r = 0; r < 8; ++r)
#pragma unroll
        for (int c = 0; c < 4; ++c) acc[r][c] = 0.0f;

    for (int stage = 0; stage < 2; ++stage) {
        __syncthreads();   // protect LDS reuse across stages
        if (stage == 0) {
            // cooperative h_d tile load: 64 rows x 32 float4
#pragma unroll
            for (int i = 0; i < 8; ++i) {
                int idx = tid + i * 256;
                int r   = idx >> 5;
                int c4  = idx & 31;
                int grow = row0 + r;
                float4 v = make_float4(0.f, 0.f, 0.f, 0.f);
                if (grow < N_DST)
                    v = ((const float4*)(h_d + (size_t)grow * IN_FEAT))[c4];
                *(float4*)&As[r][c4 * 4] = v;
            }
        } else {
            // gather-mean tile: wave handles rows wave, wave+4, ...
            for (int r = wave; r < 64; r += 4) {
                int grow = row0 + r;
                float2 a = make_float2(0.f, 0.f);
                float inv = 0.f;
                if (grow < N_DST) {
                    int off = offsets[grow];
                    int dg  = offsets[grow + 1] - off;
                    inv = (dg > 0) ? (1.0f / (float)dg) : 0.0f;
                    for (int j = 0; j < dg; j += 4) {
                        int s0 = perm[off + j];
                        int s1 = (j + 1 < dg) ? perm[off + j + 1] : -1;
                        int s2 = (j + 2 < dg) ? perm[off + j + 2] : -1;
                        int s3 = (j + 3 < dg) ? perm[off + j + 3] : -1;
                        // clamp to a safe address + mask so all 4 loads issue
                        // before any accumulation (no serialized waits)
                        int t1 = (s1 >= 0) ? s1 : s0;
                        int t2 = (s2 >= 0) ? s2 : s0;
                        int t3 = (s3 >= 0) ? s3 : s0;
                        float m1 = (s1 >= 0) ? 1.f : 0.f;
                        float m2 = (s2 >= 0) ? 1.f : 0.f;
                        float m3 = (s3 >= 0) ? 1.f : 0.f;
                        float2 v0 = ((const float2*)(h_s + (size_t)s0 * IN_FEAT))[lane];
                        float2 v1 = ((const float2*)(h_s + (size_t)t1 * IN_FEAT))[lane];
                        float2 v2 = ((const float2*)(h_s + (size_t)t2 * IN_FEAT))[lane];
                        float2 v3 = ((const float2*)(h_s + (size_t)t3 * IN_FEAT))[lane];
                        a.x += v0.x;            a.y += v0.y;
                        a.x += m1 * v1.x;       a.y += m1 * v1.y;
                        a.x += m2 * v2.x;       a.y += m2 * v2.y;
                        a.x += m3 * v3.x;       a.y += m3 * v3.y;
                    }
                }
                As[r][lane * 2]     = a.x * inv;
                As[r][lane * 2 + 1] = a.y * inv;
            }
        }
        __syncthreads();

        const float* Wp = W + (size_t)(4 * cg) * (2 * IN_FEAT) + stage * IN_FEAT;
#pragma unroll 4
        for (int k4 = 0; k4 < 32; ++k4) {
            float4 w0 = *(const float4*)(Wp + 0 * 256 + k4 * 4);
            float4 w1 = *(const float4*)(Wp + 1 * 256 + k4 * 4);
            float4 w2 = *(const float4*)(Wp + 2 * 256 + k4 * 4);
            float4 w3 = *(const float4*)(Wp + 3 * 256 + k4 * 4);
#pragma unroll
            for (int r = 0; r < 8; ++r) {
                float4 a = *(const float4*)&As[rg * 8 + r][k4 * 4];
                acc[r][0] += a.x * w0.x + a.y * w0.y + a.z * w0.z + a.w * w0.w;
                acc[r][1] += a.x * w1.x + a.y * w1.y + a.z * w1.z + a.w * w1.w;
                acc[r][2] += a.x * w2.x + a.y * w2.y + a.z * w2.z + a.w * w2.w;
                acc[r][3] += a.x * w3.x + a.y * w3.y + a.z * w3.z + a.w * w3.w;
            }
        }
    }

    float4 bb = *(const float4*)(b + 4 * cg);
#pragma unroll
    for (int r = 0; r < 8; ++r) {
        int grow = row0 + rg * 8 + r;
        if (grow < N_DST) {
            float4 o;
            o.x = acc[r][0] + bb.x;
            o.y = acc[r][1] + bb.y;
            o.z = acc[r][2] + bb.z;
            o.w = acc[r][3] + bb.w;
            *(float4*)(out + (size_t)grow * OUT_FEAT + 4 * cg) = o;
        }
    }
}

extern "C" void kernel_launch(void* const* d_in, const int* in_sizes, int n_in,
                              void* d_out, int out_size, void* d_ws, size_t ws_size,
                              hipStream_t stream) {
    const float* h_s = (const float*)d_in[0];
    const float* h_d = (const float*)d_in[1];
    const int*   src = (const int*)d_in[2];
    const int*   dst = (const int*)d_in[3];
    const float* W   = (const float*)d_in[4];
    const float* b   = (const float*)d_in[5];
    float* out = (float*)d_out;

    // workspace layout (ints), ~3 MB total
    int* deg     = (int*)d_ws;
    int* offsets = deg + N_DST;
    int* cursor  = offsets + (N_DST + 1);
    int* perm    = cursor + N_DST;

    hipMemsetAsync(deg, 0, N_DST * sizeof(int), stream);

    hist_kernel<<<(N_EDGES + 255) / 256, 256, 0, stream>>>(dst, deg);
    scan_kernel<<<1, SCAN_THREADS, 0, stream>>>(deg, offsets, cursor);
    fill_kernel<<<(N_EDGES + 255) / 256, 256, 0, stream>>>(src, dst, cursor, perm);
    fused_gemm_kernel<<<(N_DST + 63) / 64, 256, 0, stream>>>(
        h_d, h_s, offsets, perm, W, b, out);
}

// Round 3
// 430.265 us; speedup vs baseline: 1.7377x; 1.0982x over previous
//
#include <hip/hip_runtime.h>

#define N_SRC 50000
#define N_DST 50000
#define N_EDGES 600000
#define IN_FEAT 128
#define OUT_FEAT 128
#define SCAN_THREADS 1024
#define SCAN_CHUNK 49   // ceil(50000/1024)

// ---------------------------------------------------------------------------
// K1: degree histogram
// ---------------------------------------------------------------------------
__global__ __launch_bounds__(256) void hist_kernel(
    const int* __restrict__ dst, int* __restrict__ deg)
{
    int e = blockIdx.x * 256 + threadIdx.x;
    if (e < N_EDGES) atomicAdd(&deg[dst[e]], 1);
}

// ---------------------------------------------------------------------------
// K2: single-block exclusive scan. Writes offsets[0..N_DST]; overwrites deg[]
// with the exclusive prefix so it doubles as the fill cursor (saves an array
// and a memcpy).
// ---------------------------------------------------------------------------
__global__ __launch_bounds__(SCAN_THREADS) void scan_kernel(
    int* __restrict__ deg, int* __restrict__ offsets)
{
    __shared__ int part[SCAN_THREADS];
    int t = threadIdx.x;
    int begin = t * SCAN_CHUNK;
    int end   = begin + SCAN_CHUNK;
    if (begin > N_DST) begin = N_DST;
    if (end   > N_DST) end   = N_DST;

    int s = 0;
    for (int i = begin; i < end; ++i) s += deg[i];
    part[t] = s;
    __syncthreads();
    for (int o = 1; o < SCAN_THREADS; o <<= 1) {
        int v = (t >= o) ? part[t - o] : 0;
        __syncthreads();
        part[t] += v;
        __syncthreads();
    }
    int run = (t == 0) ? 0 : part[t - 1];
    for (int i = begin; i < end; ++i) {
        int d = deg[i];
        offsets[i] = run;
        deg[i]     = run;   // cursor
        run += d;
    }
    if (t == SCAN_THREADS - 1) offsets[N_DST] = part[SCAN_THREADS - 1];
}

// ---------------------------------------------------------------------------
// K3: fill edge permutation: perm slots grouped by dst row hold src ids
// ---------------------------------------------------------------------------
__global__ __launch_bounds__(256) void fill_kernel(
    const int* __restrict__ src, const int* __restrict__ dst,
    int* __restrict__ cursor, int* __restrict__ perm)
{
    int e = blockIdx.x * 256 + threadIdx.x;
    if (e < N_EDGES) {
        int d = dst[e];
        int p = atomicAdd(&cursor[d], 1);
        perm[p] = src[e];
    }
}

// ---------------------------------------------------------------------------
// K4: gather-mean, ONE WAVE PER DST ROW (50k waves -> deep latency hiding).
// 64 lanes x float2 = 128 feats. 4-edge batching so the four row loads are
// in flight together. Result (already divided by degree) written to `neigh`
// which aliases d_out (safe: K5 reads its tile before overwriting it).
// ---------------------------------------------------------------------------
__global__ __launch_bounds__(256) void gather_kernel(
    const float* __restrict__ h_s, const int* __restrict__ offsets,
    const int* __restrict__ perm, float* __restrict__ neigh)
{
    int wave = threadIdx.x >> 6;
    int lane = threadIdx.x & 63;
    int row  = blockIdx.x * 4 + wave;
    if (row >= N_DST) return;

    int off = offsets[row];
    int end = offsets[row + 1];
    int dg  = end - off;

    float2 a = make_float2(0.f, 0.f);
    for (int j = off; j < end; j += 4) {
        int s0 = perm[j];
        int s1 = (j + 1 < end) ? perm[j + 1] : -1;
        int s2 = (j + 2 < end) ? perm[j + 2] : -1;
        int s3 = (j + 3 < end) ? perm[j + 3] : -1;
        int t1 = (s1 >= 0) ? s1 : s0;
        int t2 = (s2 >= 0) ? s2 : s0;
        int t3 = (s3 >= 0) ? s3 : s0;
        float m1 = (s1 >= 0) ? 1.f : 0.f;
        float m2 = (s2 >= 0) ? 1.f : 0.f;
        float m3 = (s3 >= 0) ? 1.f : 0.f;
        float2 v0 = ((const float2*)(h_s + (size_t)s0 * IN_FEAT))[lane];
        float2 v1 = ((const float2*)(h_s + (size_t)t1 * IN_FEAT))[lane];
        float2 v2 = ((const float2*)(h_s + (size_t)t2 * IN_FEAT))[lane];
        float2 v3 = ((const float2*)(h_s + (size_t)t3 * IN_FEAT))[lane];
        a.x += v0.x + m1 * v1.x + m2 * v2.x + m3 * v3.x;
        a.y += v0.y + m1 * v1.y + m2 * v2.y + m3 * v3.y;
    }
    float inv = (dg > 0) ? (1.0f / (float)dg) : 0.0f;
    float2 o = make_float2(a.x * inv, a.y * inv);
    ((float2*)(neigh + (size_t)row * IN_FEAT))[lane] = o;
}

// ---------------------------------------------------------------------------
// K5: streaming GEMM: out = [h_d | neigh] @ W.T + b
// Block tile 64 rows x 128 cols, 256 thr, thread = 8 rows x 4 cols.
// neigh aliases out: each block reads only its own 64-row tile (staged to
// LDS, then __syncthreads) before writing those rows at the end -> safe.
// ---------------------------------------------------------------------------
__global__ __launch_bounds__(256) void gemm_kernel(
    const float* __restrict__ h_d, const float* __restrict__ neigh,
    const float* __restrict__ W, const float* __restrict__ b,
    float* __restrict__ out)
{
    __shared__ float As[64][132];

    int tid = threadIdx.x;
    int cg  = tid & 31;
    int rg  = tid >> 5;
    int row0 = blockIdx.x * 64;

    float acc[8][4];
#pragma unroll
    for (int r = 0; r < 8; ++r)
#pragma unroll
        for (int c = 0; c < 4; ++c) acc[r][c] = 0.0f;

    for (int stage = 0; stage < 2; ++stage) {
        const float* srcmat = stage ? neigh : h_d;
        __syncthreads();
#pragma unroll
        for (int i = 0; i < 8; ++i) {
            int idx = tid + i * 256;
            int r   = idx >> 5;
            int c4  = idx & 31;
            int grow = row0 + r;
            float4 v = make_float4(0.f, 0.f, 0.f, 0.f);
            if (grow < N_DST)
                v = ((const float4*)(srcmat + (size_t)grow * IN_FEAT))[c4];
            *(float4*)&As[r][c4 * 4] = v;
        }
        __syncthreads();

        const float* Wp = W + (size_t)(4 * cg) * (2 * IN_FEAT) + stage * IN_FEAT;
#pragma unroll 4
        for (int k4 = 0; k4 < 32; ++k4) {
            float4 w0 = *(const float4*)(Wp + 0 * 256 + k4 * 4);
            float4 w1 = *(const float4*)(Wp + 1 * 256 + k4 * 4);
            float4 w2 = *(const float4*)(Wp + 2 * 256 + k4 * 4);
            float4 w3 = *(const float4*)(Wp + 3 * 256 + k4 * 4);
#pragma unroll
            for (int r = 0; r < 8; ++r) {
                float4 a = *(const float4*)&As[rg * 8 + r][k4 * 4];
                acc[r][0] += a.x * w0.x + a.y * w0.y + a.z * w0.z + a.w * w0.w;
                acc[r][1] += a.x * w1.x + a.y * w1.y + a.z * w1.z + a.w * w1.w;
                acc[r][2] += a.x * w2.x + a.y * w2.y + a.z * w2.z + a.w * w2.w;
                acc[r][3] += a.x * w3.x + a.y * w3.y + a.z * w3.z + a.w * w3.w;
            }
        }
    }

    float4 bb = *(const float4*)(b + 4 * cg);
#pragma unroll
    for (int r = 0; r < 8; ++r) {
        int grow = row0 + rg * 8 + r;
        if (grow < N_DST) {
            float4 o;
            o.x = acc[r][0] + bb.x;
            o.y = acc[r][1] + bb.y;
            o.z = acc[r][2] + bb.z;
            o.w = acc[r][3] + bb.w;
            *(float4*)(out + (size_t)grow * OUT_FEAT + 4 * cg) = o;
        }
    }
}

extern "C" void kernel_launch(void* const* d_in, const int* in_sizes, int n_in,
                              void* d_out, int out_size, void* d_ws, size_t ws_size,
                              hipStream_t stream) {
    const float* h_s = (const float*)d_in[0];
    const float* h_d = (const float*)d_in[1];
    const int*   src = (const int*)d_in[2];
    const int*   dst = (const int*)d_in[3];
    const float* W   = (const float*)d_in[4];
    const float* b   = (const float*)d_in[5];
    float* out = (float*)d_out;

    // workspace (ints, ~2.8 MB)
    int* deg     = (int*)d_ws;            // histogram, then fill-cursor
    int* offsets = deg + N_DST;           // N_DST+1
    int* perm    = offsets + (N_DST + 1); // N_EDGES

    // d_out doubles as the neigh_mean buffer (25.6 MB saved from ws)
    float* neigh = out;

    hipMemsetAsync(deg, 0, N_DST * sizeof(int), stream);

    hist_kernel<<<(N_EDGES + 255) / 256, 256, 0, stream>>>(dst, deg);
    scan_kernel<<<1, SCAN_THREADS, 0, stream>>>(deg, offsets);
    fill_kernel<<<(N_EDGES + 255) / 256, 256, 0, stream>>>(src, dst, deg, perm);
    gather_kernel<<<(N_DST + 3) / 4, 256, 0, stream>>>(h_s, offsets, perm, neigh);
    gemm_kernel<<<(N_DST + 63) / 64, 256, 0, stream>>>(h_d, neigh, W, b, out);
}

// Round 4
// 373.773 us; speedup vs baseline: 2.0004x; 1.1511x over previous
//
#include <hip/hip_runtime.h>
#include <hip/hip_bf16.h>

#define N_SRC 50000
#define N_DST 50000
#define N_EDGES 600000
#define IN_FEAT 128
#define OUT_FEAT 128
#define SCAN_THREADS 1024
#define SCAN_CHUNK 49   // ceil(50000/1024)

// ---------------------------------------------------------------------------
// K0a: transpose W [128][256] -> Wt [256][128] (131 KB, L2-resident after)
// ---------------------------------------------------------------------------
__global__ __launch_bounds__(256) void transpose_w_kernel(
    const float* __restrict__ W, float* __restrict__ Wt)
{
    int idx = blockIdx.x * 256 + threadIdx.x;   // 32768 elements
    int c = idx >> 8;          // 0..127  (W row)
    int k = idx & 255;         // 0..255  (W col)
    Wt[k * 128 + c] = W[c * 256 + k];
}

// ---------------------------------------------------------------------------
// K0b: convert h_s to bf16 (RNE), 4 elems/thread
// ---------------------------------------------------------------------------
__global__ __launch_bounds__(256) void cvt_bf16_kernel(
    const float* __restrict__ h_s, __hip_bfloat16* __restrict__ hsb)
{
    int idx = blockIdx.x * 256 + threadIdx.x;   // over N_SRC*IN_FEAT/4
    float4 v = ((const float4*)h_s)[idx];
    __hip_bfloat16 o[4];
    o[0] = __float2bfloat16(v.x);
    o[1] = __float2bfloat16(v.y);
    o[2] = __float2bfloat16(v.z);
    o[3] = __float2bfloat16(v.w);
    *(ushort4*)(hsb + idx * 4) = *(ushort4*)o;
}

// ---------------------------------------------------------------------------
// K1: degree histogram
// ---------------------------------------------------------------------------
__global__ __launch_bounds__(256) void hist_kernel(
    const int* __restrict__ dst, int* __restrict__ deg)
{
    int e = blockIdx.x * 256 + threadIdx.x;
    if (e < N_EDGES) atomicAdd(&deg[dst[e]], 1);
}

// ---------------------------------------------------------------------------
// K2: single-block exclusive scan; deg[] becomes the fill cursor
// ---------------------------------------------------------------------------
__global__ __launch_bounds__(SCAN_THREADS) void scan_kernel(
    int* __restrict__ deg, int* __restrict__ offsets)
{
    __shared__ int part[SCAN_THREADS];
    int t = threadIdx.x;
    int begin = t * SCAN_CHUNK;
    int end   = begin + SCAN_CHUNK;
    if (begin > N_DST) begin = N_DST;
    if (end   > N_DST) end   = N_DST;

    int s = 0;
    for (int i = begin; i < end; ++i) s += deg[i];
    part[t] = s;
    __syncthreads();
    for (int o = 1; o < SCAN_THREADS; o <<= 1) {
        int v = (t >= o) ? part[t - o] : 0;
        __syncthreads();
        part[t] += v;
        __syncthreads();
    }
    int run = (t == 0) ? 0 : part[t - 1];
    for (int i = begin; i < end; ++i) {
        int d = deg[i];
        offsets[i] = run;
        deg[i]     = run;   // cursor
        run += d;
    }
    if (t == SCAN_THREADS - 1) offsets[N_DST] = part[SCAN_THREADS - 1];
}

// ---------------------------------------------------------------------------
// K3: fill edge permutation
// ---------------------------------------------------------------------------
__global__ __launch_bounds__(256) void fill_kernel(
    const int* __restrict__ src, const int* __restrict__ dst,
    int* __restrict__ cursor, int* __restrict__ perm)
{
    int e = blockIdx.x * 256 + threadIdx.x;
    if (e < N_EDGES) {
        int d = dst[e];
        int p = atomicAdd(&cursor[d], 1);
        perm[p] = src[e];
    }
}

// ---------------------------------------------------------------------------
// K4: gather-mean from bf16 source rows, one wave per dst row.
// 64 lanes x bf16x2 (4 B) = 256 B per row read; f32 accumulation (exact
// expand via bit shift). 4-edge batching keeps 4 row loads in flight.
// Writes f32 mean to neigh (aliases d_out; GEMM blocks only touch own rows).
// ---------------------------------------------------------------------------
__global__ __launch_bounds__(256) void gather_kernel(
    const ushort* __restrict__ hsb, const int* __restrict__ offsets,
    const int* __restrict__ perm, float* __restrict__ neigh)
{
    int wave = threadIdx.x >> 6;
    int lane = threadIdx.x & 63;
    int row  = blockIdx.x * 4 + wave;
    if (row >= N_DST) return;

    int off = offsets[row];
    int end = offsets[row + 1];
    int dg  = end - off;

    float ax = 0.f, ay = 0.f;
    for (int j = off; j < end; j += 4) {
        int s0 = perm[j];
        int s1 = (j + 1 < end) ? perm[j + 1] : -1;
        int s2 = (j + 2 < end) ? perm[j + 2] : -1;
        int s3 = (j + 3 < end) ? perm[j + 3] : -1;
        int t1 = (s1 >= 0) ? s1 : s0;
        int t2 = (s2 >= 0) ? s2 : s0;
        int t3 = (s3 >= 0) ? s3 : s0;
        float m1 = (s1 >= 0) ? 1.f : 0.f;
        float m2 = (s2 >= 0) ? 1.f : 0.f;
        float m3 = (s3 >= 0) ? 1.f : 0.f;
        ushort2 u0 = ((const ushort2*)(hsb + (size_t)s0 * IN_FEAT))[lane];
        ushort2 u1 = ((const ushort2*)(hsb + (size_t)t1 * IN_FEAT))[lane];
        ushort2 u2 = ((const ushort2*)(hsb + (size_t)t2 * IN_FEAT))[lane];
        ushort2 u3 = ((const ushort2*)(hsb + (size_t)t3 * IN_FEAT))[lane];
        ax += __uint_as_float((unsigned)u0.x << 16);
        ay += __uint_as_float((unsigned)u0.y << 16);
        ax += m1 * __uint_as_float((unsigned)u1.x << 16);
        ay += m1 * __uint_as_float((unsigned)u1.y << 16);
        ax += m2 * __uint_as_float((unsigned)u2.x << 16);
        ay += m2 * __uint_as_float((unsigned)u2.y << 16);
        ax += m3 * __uint_as_float((unsigned)u3.x << 16);
        ay += m3 * __uint_as_float((unsigned)u3.y << 16);
    }
    float inv = (dg > 0) ? (1.0f / (float)dg) : 0.0f;
    ((float2*)(neigh + (size_t)row * IN_FEAT))[lane] =
        make_float2(ax * inv, ay * inv);
}

// ---------------------------------------------------------------------------
// K5: GEMM out = [h_d | neigh] @ W.T + b using pre-transposed Wt[256][128].
// Block: 64 rows x 128 cols, 256 threads; thread: 4 rows x (4+4) cols.
//   rg = tid>>4 -> rows rg*4..+3 ; cg = tid&15 -> cols 4cg..+3 and 64+4cg..+3
// A-tile (64x32 per K-chunk) in LDS (k-minor, rg-broadcast reads).
// Wt reads: lanes span contiguous columns -> 256 B wave fetch, L1/L2-served.
// neigh aliases out: block reads only its own 64 rows before writing them.
// ---------------------------------------------------------------------------
__global__ __launch_bounds__(256) void gemm_kernel(
    const float* __restrict__ h_d, const float* __restrict__ neigh,
    const float* __restrict__ Wt, const float* __restrict__ b,
    float* __restrict__ out)
{
    __shared__ float As[64][33];

    int tid = threadIdx.x;
    int cg  = tid & 15;
    int rg  = tid >> 4;
    int row0 = blockIdx.x * 64;

    float acc[4][8];
#pragma unroll
    for (int r = 0; r < 4; ++r)
#pragma unroll
        for (int c = 0; c < 8; ++c) acc[r][c] = 0.0f;

    for (int chunk = 0; chunk < 8; ++chunk) {
        int koff = chunk * 32;                       // 0..224 (concat-K)
        const float* srcmat = (chunk < 4) ? h_d : neigh;
        int base4 = (chunk & 3) * 8;                 // float4 col base in srcmat

        __syncthreads();
        // stage A-tile: 64 rows x 8 float4, 2 per thread
#pragma unroll
        for (int i = 0; i < 2; ++i) {
            int idx = tid + i * 256;
            int r   = idx >> 3;
            int c4  = idx & 7;
            int grow = row0 + r;
            float4 v = make_float4(0.f, 0.f, 0.f, 0.f);
            if (grow < N_DST)
                v = ((const float4*)(srcmat + (size_t)grow * IN_FEAT))[base4 + c4];
            *(float4*)&As[r][c4 * 4] = v;
        }
        __syncthreads();

#pragma unroll 4
        for (int k4 = 0; k4 < 8; ++k4) {
            float4 a0 = *(const float4*)&As[rg * 4 + 0][k4 * 4];
            float4 a1 = *(const float4*)&As[rg * 4 + 1][k4 * 4];
            float4 a2 = *(const float4*)&As[rg * 4 + 2][k4 * 4];
            float4 a3 = *(const float4*)&As[rg * 4 + 3][k4 * 4];
#pragma unroll
            for (int kj = 0; kj < 4; ++kj) {
                const float4* wrow =
                    (const float4*)(Wt + (size_t)(koff + k4 * 4 + kj) * 128);
                float4 wl = wrow[cg];
                float4 wh = wrow[16 + cg];
                float a[4] = {0.f, 0.f, 0.f, 0.f};
                a[0] = (kj == 0) ? a0.x : (kj == 1) ? a0.y : (kj == 2) ? a0.z : a0.w;
                a[1] = (kj == 0) ? a1.x : (kj == 1) ? a1.y : (kj == 2) ? a1.z : a1.w;
                a[2] = (kj == 0) ? a2.x : (kj == 1) ? a2.y : (kj == 2) ? a2.z : a2.w;
                a[3] = (kj == 0) ? a3.x : (kj == 1) ? a3.y : (kj == 2) ? a3.z : a3.w;
#pragma unroll
                for (int r = 0; r < 4; ++r) {
                    acc[r][0] += a[r] * wl.x;
                    acc[r][1] += a[r] * wl.y;
                    acc[r][2] += a[r] * wl.z;
                    acc[r][3] += a[r] * wl.w;
                    acc[r][4] += a[r] * wh.x;
                    acc[r][5] += a[r] * wh.y;
                    acc[r][6] += a[r] * wh.z;
                    acc[r][7] += a[r] * wh.w;
                }
            }
        }
    }

    float4 bl = ((const float4*)b)[cg];
    float4 bh = ((const float4*)b)[16 + cg];
#pragma unroll
    for (int r = 0; r < 4; ++r) {
        int grow = row0 + rg * 4 + r;
        if (grow < N_DST) {
            float4 ol, oh;
            ol.x = acc[r][0] + bl.x;  ol.y = acc[r][1] + bl.y;
            ol.z = acc[r][2] + bl.z;  ol.w = acc[r][3] + bl.w;
            oh.x = acc[r][4] + bh.x;  oh.y = acc[r][5] + bh.y;
            oh.z = acc[r][6] + bh.z;  oh.w = acc[r][7] + bh.w;
            ((float4*)(out + (size_t)grow * OUT_FEAT))[cg]      = ol;
            ((float4*)(out + (size_t)grow * OUT_FEAT))[16 + cg] = oh;
        }
    }
}

extern "C" void kernel_launch(void* const* d_in, const int* in_sizes, int n_in,
                              void* d_out, int out_size, void* d_ws, size_t ws_size,
                              hipStream_t stream) {
    const float* h_s = (const float*)d_in[0];
    const float* h_d = (const float*)d_in[1];
    const int*   src = (const int*)d_in[2];
    const int*   dst = (const int*)d_in[3];
    const float* W   = (const float*)d_in[4];
    const float* b   = (const float*)d_in[5];
    float* out = (float*)d_out;

    // workspace layout
    int* deg     = (int*)d_ws;                 // N_DST (hist, then cursor)
    int* offsets = deg + N_DST;                // N_DST+1
    int* perm    = offsets + (N_DST + 1);      // N_EDGES
    int  ihead   = N_DST + (N_DST + 1) + N_EDGES;
    ihead = (ihead + 3) & ~3;                  // 16 B align
    __hip_bfloat16* hsb = (__hip_bfloat16*)((int*)d_ws + ihead);   // N_SRC*IN_FEAT
    float* Wt = (float*)(hsb + (size_t)N_SRC * IN_FEAT);           // 256*128
    // total ws: ~2.8 MB ints + 12.8 MB bf16 + 131 KB = ~15.8 MB

    float* neigh = out;   // d_out doubles as the mean buffer

    hipMemsetAsync(deg, 0, N_DST * sizeof(int), stream);

    transpose_w_kernel<<<(OUT_FEAT * 2 * IN_FEAT) / 256, 256, 0, stream>>>(W, Wt);
    cvt_bf16_kernel<<<(N_SRC * IN_FEAT / 4) / 256, 256, 0, stream>>>(h_s, hsb);
    hist_kernel<<<(N_EDGES + 255) / 256, 256, 0, stream>>>(dst, deg);
    scan_kernel<<<1, SCAN_THREADS, 0, stream>>>(deg, offsets);
    fill_kernel<<<(N_EDGES + 255) / 256, 256, 0, stream>>>(src, dst, deg, perm);
    gather_kernel<<<(N_DST + 3) / 4, 256, 0, stream>>>(
        (const ushort*)hsb, offsets, perm, neigh);
    gemm_kernel<<<(N_DST + 63) / 64, 256, 0, stream>>>(h_d, neigh, Wt, b, out);
}

// Round 5
// 277.878 us; speedup vs baseline: 2.6907x; 1.3451x over previous
//
#include <hip/hip_runtime.h>
#include <hip/hip_bf16.h>

#define N_SRC 50000
#define N_DST 50000
#define N_EDGES 600000
#define IN_FEAT 128
#define OUT_FEAT 128
#define NB 196   // ceil(N_DST/256)

// ---------------------------------------------------------------------------
// K0a: transpose W [128][256] -> Wt [256][128]
// ---------------------------------------------------------------------------
__global__ __launch_bounds__(256) void transpose_w_kernel(
    const float* __restrict__ W, float* __restrict__ Wt)
{
    int idx = blockIdx.x * 256 + threadIdx.x;   // 32768 elements
    int c = idx >> 8;          // 0..127  (W row)
    int k = idx & 255;         // 0..255  (W col)
    Wt[k * 128 + c] = W[c * 256 + k];
}

// ---------------------------------------------------------------------------
// K0b: convert h_s to bf16 (RNE), 4 elems/thread
// ---------------------------------------------------------------------------
__global__ __launch_bounds__(256) void cvt_bf16_kernel(
    const float* __restrict__ h_s, __hip_bfloat16* __restrict__ hsb)
{
    int idx = blockIdx.x * 256 + threadIdx.x;   // over N_SRC*IN_FEAT/4
    float4 v = ((const float4*)h_s)[idx];
    __hip_bfloat16 o[4];
    o[0] = __float2bfloat16(v.x);
    o[1] = __float2bfloat16(v.y);
    o[2] = __float2bfloat16(v.z);
    o[3] = __float2bfloat16(v.w);
    *(ushort4*)(hsb + idx * 4) = *(ushort4*)o;
}

// ---------------------------------------------------------------------------
// K1: degree histogram
// ---------------------------------------------------------------------------
__global__ __launch_bounds__(256) void hist_kernel(
    const int* __restrict__ dst, int* __restrict__ deg)
{
    int e = blockIdx.x * 256 + threadIdx.x;
    if (e < N_EDGES) atomicAdd(&deg[dst[e]], 1);
}

// ---------------------------------------------------------------------------
// K2a: per-block sum of deg (196 blocks x 256)
// ---------------------------------------------------------------------------
__global__ __launch_bounds__(256) void blockreduce_kernel(
    const int* __restrict__ deg, int* __restrict__ bsum)
{
    __shared__ int sh[256];
    int i = blockIdx.x * 256 + threadIdx.x;
    sh[threadIdx.x] = (i < N_DST) ? deg[i] : 0;
    __syncthreads();
#pragma unroll
    for (int o = 128; o > 0; o >>= 1) {
        if (threadIdx.x < o) sh[threadIdx.x] += sh[threadIdx.x + o];
        __syncthreads();
    }
    if (threadIdx.x == 0) bsum[blockIdx.x] = sh[0];
}

// ---------------------------------------------------------------------------
// K2b: scan the 196 block sums (single 256-thr block), write block offsets
// ---------------------------------------------------------------------------
__global__ __launch_bounds__(256) void scanb_kernel(
    const int* __restrict__ bsum, int* __restrict__ boff,
    int* __restrict__ offsets)
{
    __shared__ int sh[256];
    int t = threadIdx.x;
    int v = (t < NB) ? bsum[t] : 0;
    sh[t] = v;
    __syncthreads();
#pragma unroll
    for (int o = 1; o < 256; o <<= 1) {
        int u = (t >= o) ? sh[t - o] : 0;
        __syncthreads();
        sh[t] += u;
        __syncthreads();
    }
    if (t < NB) boff[t] = sh[t] - v;          // exclusive
    if (t == 255) offsets[N_DST] = sh[255];   // total (= N_EDGES)
}

// ---------------------------------------------------------------------------
// K2c: per-block exclusive scan + block offset -> offsets[] and cursor (deg)
// ---------------------------------------------------------------------------
__global__ __launch_bounds__(256) void scanc_kernel(
    int* __restrict__ deg, const int* __restrict__ boff,
    int* __restrict__ offsets)
{
    __shared__ int sh[256];
    int i = blockIdx.x * 256 + threadIdx.x;
    int t = threadIdx.x;
    int v = (i < N_DST) ? deg[i] : 0;
    sh[t] = v;
    __syncthreads();
#pragma unroll
    for (int o = 1; o < 256; o <<= 1) {
        int u = (t >= o) ? sh[t - o] : 0;
        __syncthreads();
        sh[t] += u;
        __syncthreads();
    }
    int excl = sh[t] - v + boff[blockIdx.x];
    if (i < N_DST) {
        offsets[i] = excl;
        deg[i]     = excl;   // fill cursor
    }
}

// ---------------------------------------------------------------------------
// K3: fill edge permutation
// ---------------------------------------------------------------------------
__global__ __launch_bounds__(256) void fill_kernel(
    const int* __restrict__ src, const int* __restrict__ dst,
    int* __restrict__ cursor, int* __restrict__ perm)
{
    int e = blockIdx.x * 256 + threadIdx.x;
    if (e < N_EDGES) {
        int d = dst[e];
        int p = atomicAdd(&cursor[d], 1);
        perm[p] = src[e];
    }
}

// ---------------------------------------------------------------------------
// K4: gather-mean from bf16 source rows, one wave per dst row.
// ---------------------------------------------------------------------------
__global__ __launch_bounds__(256) void gather_kernel(
    const ushort* __restrict__ hsb, const int* __restrict__ offsets,
    const int* __restrict__ perm, float* __restrict__ neigh)
{
    int wave = threadIdx.x >> 6;
    int lane = threadIdx.x & 63;
    int row  = blockIdx.x * 4 + wave;
    if (row >= N_DST) return;

    int off = offsets[row];
    int end = offsets[row + 1];
    int dg  = end - off;

    float ax = 0.f, ay = 0.f;
    for (int j = off; j < end; j += 4) {
        int s0 = perm[j];
        int s1 = (j + 1 < end) ? perm[j + 1] : -1;
        int s2 = (j + 2 < end) ? perm[j + 2] : -1;
        int s3 = (j + 3 < end) ? perm[j + 3] : -1;
        int t1 = (s1 >= 0) ? s1 : s0;
        int t2 = (s2 >= 0) ? s2 : s0;
        int t3 = (s3 >= 0) ? s3 : s0;
        float m1 = (s1 >= 0) ? 1.f : 0.f;
        float m2 = (s2 >= 0) ? 1.f : 0.f;
        float m3 = (s3 >= 0) ? 1.f : 0.f;
        ushort2 u0 = ((const ushort2*)(hsb + (size_t)s0 * IN_FEAT))[lane];
        ushort2 u1 = ((const ushort2*)(hsb + (size_t)t1 * IN_FEAT))[lane];
        ushort2 u2 = ((const ushort2*)(hsb + (size_t)t2 * IN_FEAT))[lane];
        ushort2 u3 = ((const ushort2*)(hsb + (size_t)t3 * IN_FEAT))[lane];
        ax += __uint_as_float((unsigned)u0.x << 16);
        ay += __uint_as_float((unsigned)u0.y << 16);
        ax += m1 * __uint_as_float((unsigned)u1.x << 16);
        ay += m1 * __uint_as_float((unsigned)u1.y << 16);
        ax += m2 * __uint_as_float((unsigned)u2.x << 16);
        ay += m2 * __uint_as_float((unsigned)u2.y << 16);
        ax += m3 * __uint_as_float((unsigned)u3.x << 16);
        ay += m3 * __uint_as_float((unsigned)u3.y << 16);
    }
    float inv = (dg > 0) ? (1.0f / (float)dg) : 0.0f;
    ((float2*)(neigh + (size_t)row * IN_FEAT))[lane] =
        make_float2(ax * inv, ay * inv);
}

// ---------------------------------------------------------------------------
// K5: GEMM out = [h_d | neigh] @ W.T + b using pre-transposed Wt[256][128].
// ---------------------------------------------------------------------------
__global__ __launch_bounds__(256) void gemm_kernel(
    const float* __restrict__ h_d, const float* __restrict__ neigh,
    const float* __restrict__ Wt, const float* __restrict__ b,
    float* __restrict__ out)
{
    __shared__ float As[64][33];

    int tid = threadIdx.x;
    int cg  = tid & 15;
    int rg  = tid >> 4;
    int row0 = blockIdx.x * 64;

    float acc[4][8];
#pragma unroll
    for (int r = 0; r < 4; ++r)
#pragma unroll
        for (int c = 0; c < 8; ++c) acc[r][c] = 0.0f;

    for (int chunk = 0; chunk < 8; ++chunk) {
        int koff = chunk * 32;                       // 0..224 (concat-K)
        const float* srcmat = (chunk < 4) ? h_d : neigh;
        int base4 = (chunk & 3) * 8;

        __syncthreads();
#pragma unroll
        for (int i = 0; i < 2; ++i) {
            int idx = tid + i * 256;
            int r   = idx >> 3;
            int c4  = idx & 7;
            int grow = row0 + r;
            float4 v = make_float4(0.f, 0.f, 0.f, 0.f);
            if (grow < N_DST)
                v = ((const float4*)(srcmat + (size_t)grow * IN_FEAT))[base4 + c4];
            *(float4*)&As[r][c4 * 4] = v;
        }
        __syncthreads();

#pragma unroll 4
        for (int k4 = 0; k4 < 8; ++k4) {
            float4 a0 = *(const float4*)&As[rg * 4 + 0][k4 * 4];
            float4 a1 = *(const float4*)&As[rg * 4 + 1][k4 * 4];
            float4 a2 = *(const float4*)&As[rg * 4 + 2][k4 * 4];
            float4 a3 = *(const float4*)&As[rg * 4 + 3][k4 * 4];
#pragma unroll
            for (int kj = 0; kj < 4; ++kj) {
                const float4* wrow =
                    (const float4*)(Wt + (size_t)(koff + k4 * 4 + kj) * 128);
                float4 wl = wrow[cg];
                float4 wh = wrow[16 + cg];
                float a[4];
                a[0] = (kj == 0) ? a0.x : (kj == 1) ? a0.y : (kj == 2) ? a0.z : a0.w;
                a[1] = (kj == 0) ? a1.x : (kj == 1) ? a1.y : (kj == 2) ? a1.z : a1.w;
                a[2] = (kj == 0) ? a2.x : (kj == 1) ? a2.y : (kj == 2) ? a2.z : a2.w;
                a[3] = (kj == 0) ? a3.x : (kj == 1) ? a3.y : (kj == 2) ? a3.z : a3.w;
#pragma unroll
                for (int r = 0; r < 4; ++r) {
                    acc[r][0] += a[r] * wl.x;
                    acc[r][1] += a[r] * wl.y;
                    acc[r][2] += a[r] * wl.z;
                    acc[r][3] += a[r] * wl.w;
                    acc[r][4] += a[r] * wh.x;
                    acc[r][5] += a[r] * wh.y;
                    acc[r][6] += a[r] * wh.z;
                    acc[r][7] += a[r] * wh.w;
                }
            }
        }
    }

    float4 bl = ((const float4*)b)[cg];
    float4 bh = ((const float4*)b)[16 + cg];
#pragma unroll
    for (int r = 0; r < 4; ++r) {
        int grow = row0 + rg * 4 + r;
        if (grow < N_DST) {
            float4 ol, oh;
            ol.x = acc[r][0] + bl.x;  ol.y = acc[r][1] + bl.y;
            ol.z = acc[r][2] + bl.z;  ol.w = acc[r][3] + bl.w;
            oh.x = acc[r][4] + bh.x;  oh.y = acc[r][5] + bh.y;
            oh.z = acc[r][6] + bh.z;  oh.w = acc[r][7] + bh.w;
            ((float4*)(out + (size_t)grow * OUT_FEAT))[cg]      = ol;
            ((float4*)(out + (size_t)grow * OUT_FEAT))[16 + cg] = oh;
        }
    }
}

extern "C" void kernel_launch(void* const* d_in, const int* in_sizes, int n_in,
                              void* d_out, int out_size, void* d_ws, size_t ws_size,
                              hipStream_t stream) {
    const float* h_s = (const float*)d_in[0];
    const float* h_d = (const float*)d_in[1];
    const int*   src = (const int*)d_in[2];
    const int*   dst = (const int*)d_in[3];
    const float* W   = (const float*)d_in[4];
    const float* b   = (const float*)d_in[5];
    float* out = (float*)d_out;

    // workspace layout
    int* deg     = (int*)d_ws;                 // N_DST (hist, then cursor)
    int* offsets = deg + N_DST;                // N_DST+1
    int* perm    = offsets + (N_DST + 1);      // N_EDGES
    int* bsum    = perm + N_EDGES;             // NB
    int* boff    = bsum + NB;                  // NB
    int  ihead   = N_DST + (N_DST + 1) + N_EDGES + 2 * NB;
    ihead = (ihead + 3) & ~3;                  // 16 B align
    __hip_bfloat16* hsb = (__hip_bfloat16*)((int*)d_ws + ihead);   // N_SRC*IN_FEAT
    float* Wt = (float*)(hsb + (size_t)N_SRC * IN_FEAT);           // 256*128

    float* neigh = out;   // d_out doubles as the mean buffer

    hipMemsetAsync(deg, 0, N_DST * sizeof(int), stream);

    transpose_w_kernel<<<(OUT_FEAT * 2 * IN_FEAT) / 256, 256, 0, stream>>>(W, Wt);
    cvt_bf16_kernel<<<(N_SRC * IN_FEAT / 4) / 256, 256, 0, stream>>>(h_s, hsb);
    hist_kernel<<<(N_EDGES + 255) / 256, 256, 0, stream>>>(dst, deg);
    blockreduce_kernel<<<NB, 256, 0, stream>>>(deg, bsum);
    scanb_kernel<<<1, 256, 0, stream>>>(bsum, boff, offsets);
    scanc_kernel<<<NB, 256, 0, stream>>>(deg, boff, offsets);
    fill_kernel<<<(N_EDGES + 255) / 256, 256, 0, stream>>>(src, dst, deg, perm);
    gather_kernel<<<(N_DST + 3) / 4, 256, 0, stream>>>(
        (const ushort*)hsb, offsets, perm, neigh);
    gemm_kernel<<<(N_DST + 63) / 64, 256, 0, stream>>>(h_d, neigh, Wt, b, out);
}

// Round 6
// 243.587 us; speedup vs baseline: 3.0695x; 1.1408x over previous
//
#include <hip/hip_runtime.h>
#include <hip/hip_bf16.h>

#define N_SRC 50000
#define N_DST 50000
#define N_EDGES 600000
#define IN_FEAT 128
#define OUT_FEAT 128
#define NB 196   // ceil(N_DST/256)

typedef __attribute__((ext_vector_type(8))) short short8;   // 8 bf16 = 4 VGPRs
typedef __attribute__((ext_vector_type(4))) float float4v;  // MFMA C/D

// ---------------------------------------------------------------------------
// K0: f32 -> bf16 (RNE), 4 elems/thread. Used for h_s, h_d, W.
// ---------------------------------------------------------------------------
__global__ __launch_bounds__(256) void cvt_bf16_kernel(
    const float* __restrict__ in, ushort* __restrict__ outp)
{
    int idx = blockIdx.x * 256 + threadIdx.x;
    float4 v = ((const float4*)in)[idx];
    __hip_bfloat16 o[4];
    o[0] = __float2bfloat16(v.x);
    o[1] = __float2bfloat16(v.y);
    o[2] = __float2bfloat16(v.z);
    o[3] = __float2bfloat16(v.w);
    *(ushort4*)(outp + idx * 4) = *(ushort4*)o;
}

// ---------------------------------------------------------------------------
// K1: degree histogram
// ---------------------------------------------------------------------------
__global__ __launch_bounds__(256) void hist_kernel(
    const int* __restrict__ dst, int* __restrict__ deg)
{
    int e = blockIdx.x * 256 + threadIdx.x;
    if (e < N_EDGES) atomicAdd(&deg[dst[e]], 1);
}

// ---------------------------------------------------------------------------
// K2a: per-block sum of deg (196 blocks x 256)
// ---------------------------------------------------------------------------
__global__ __launch_bounds__(256) void blockreduce_kernel(
    const int* __restrict__ deg, int* __restrict__ bsum)
{
    __shared__ int sh[256];
    int i = blockIdx.x * 256 + threadIdx.x;
    sh[threadIdx.x] = (i < N_DST) ? deg[i] : 0;
    __syncthreads();
#pragma unroll
    for (int o = 128; o > 0; o >>= 1) {
        if (threadIdx.x < o) sh[threadIdx.x] += sh[threadIdx.x + o];
        __syncthreads();
    }
    if (threadIdx.x == 0) bsum[blockIdx.x] = sh[0];
}

// ---------------------------------------------------------------------------
// K2b: scan the 196 block sums (single 256-thr block)
// ---------------------------------------------------------------------------
__global__ __launch_bounds__(256) void scanb_kernel(
    const int* __restrict__ bsum, int* __restrict__ boff,
    int* __restrict__ offsets)
{
    __shared__ int sh[256];
    int t = threadIdx.x;
    int v = (t < NB) ? bsum[t] : 0;
    sh[t] = v;
    __syncthreads();
#pragma unroll
    for (int o = 1; o < 256; o <<= 1) {
        int u = (t >= o) ? sh[t - o] : 0;
        __syncthreads();
        sh[t] += u;
        __syncthreads();
    }
    if (t < NB) boff[t] = sh[t] - v;          // exclusive
    if (t == 255) offsets[N_DST] = sh[255];   // total
}

// ---------------------------------------------------------------------------
// K2c: per-block exclusive scan + block offset -> offsets[] + cursor (deg)
// ---------------------------------------------------------------------------
__global__ __launch_bounds__(256) void scanc_kernel(
    int* __restrict__ deg, const int* __restrict__ boff,
    int* __restrict__ offsets)
{
    __shared__ int sh[256];
    int i = blockIdx.x * 256 + threadIdx.x;
    int t = threadIdx.x;
    int v = (i < N_DST) ? deg[i] : 0;
    sh[t] = v;
    __syncthreads();
#pragma unroll
    for (int o = 1; o < 256; o <<= 1) {
        int u = (t >= o) ? sh[t - o] : 0;
        __syncthreads();
        sh[t] += u;
        __syncthreads();
    }
    int excl = sh[t] - v + boff[blockIdx.x];
    if (i < N_DST) {
        offsets[i] = excl;
        deg[i]     = excl;   // fill cursor
    }
}

// ---------------------------------------------------------------------------
// K3: fill edge permutation
// ---------------------------------------------------------------------------
__global__ __launch_bounds__(256) void fill_kernel(
    const int* __restrict__ src, const int* __restrict__ dst,
    int* __restrict__ cursor, int* __restrict__ perm)
{
    int e = blockIdx.x * 256 + threadIdx.x;
    if (e < N_EDGES) {
        int d = dst[e];
        int p = atomicAdd(&cursor[d], 1);
        perm[p] = src[e];
    }
}

// ---------------------------------------------------------------------------
// K4: gather-mean, one wave per dst row, bf16 in -> f32 acc -> bf16 out.
// 8-edge batching keeps 8 row loads in flight per iteration.
// ---------------------------------------------------------------------------
__global__ __launch_bounds__(256) void gather_kernel(
    const ushort* __restrict__ hsb, const int* __restrict__ offsets,
    const int* __restrict__ perm, ushort* __restrict__ neighb)
{
    int wave = threadIdx.x >> 6;
    int lane = threadIdx.x & 63;
    int row  = blockIdx.x * 4 + wave;
    if (row >= N_DST) return;

    int off = offsets[row];
    int end = offsets[row + 1];
    int dg  = end - off;

    float ax = 0.f, ay = 0.f;
    for (int j = off; j < end; j += 8) {
        int   s[8];
        float m[8];
        int s0 = perm[j];
#pragma unroll
        for (int q = 0; q < 8; ++q) {
            bool ok = (j + q < end);
            s[q] = ok ? perm[j + q] : s0;
            m[q] = ok ? 1.f : 0.f;
        }
        ushort2 u[8];
#pragma unroll
        for (int q = 0; q < 8; ++q)
            u[q] = ((const ushort2*)(hsb + (size_t)s[q] * IN_FEAT))[lane];
#pragma unroll
        for (int q = 0; q < 8; ++q) {
            ax += m[q] * __uint_as_float((unsigned)u[q].x << 16);
            ay += m[q] * __uint_as_float((unsigned)u[q].y << 16);
        }
    }
    float inv = (dg > 0) ? (1.0f / (float)dg) : 0.0f;
    __hip_bfloat16 ox = __float2bfloat16(ax * inv);
    __hip_bfloat16 oy = __float2bfloat16(ay * inv);
    ushort2 o = make_ushort2(*(ushort*)&ox, *(ushort*)&oy);
    ((ushort2*)(neighb + (size_t)row * IN_FEAT))[lane] = o;
}

// ---------------------------------------------------------------------------
// K5: MFMA bf16 GEMM: out = [hdb | neighb] @ Wb.T + b
// Block: 4 waves, 64 rows x 128 cols. Wave: 16-row strip, 8 n-tiles.
// A-frag: A[m=lane&15][k=(lane>>4)*8+j] -> 16 B contiguous per lane.
// B-frag: Wb[n=nt*16+(lane&15)][k=(lane>>4)*8+j] -> 16 B contiguous (Wb is
// bf16 W in native [128][256] layout; no transpose needed).
// C/D: col=lane&15, row=(lane>>4)*4+reg  [verified m89/m91].
// ---------------------------------------------------------------------------
__global__ __launch_bounds__(256) void gemm_mfma_kernel(
    const ushort* __restrict__ hdb, const ushort* __restrict__ neighb,
    const ushort* __restrict__ Wb, const float* __restrict__ b,
    float* __restrict__ out)
{
    int tid  = threadIdx.x;
    int wave = tid >> 6;
    int lane = tid & 63;
    int row0 = blockIdx.x * 64 + wave * 16;

    int lm = lane & 15;
    int lk = (lane >> 4) * 8;

    float4v acc[8];
#pragma unroll
    for (int nt = 0; nt < 8; ++nt) acc[nt] = (float4v){0.f, 0.f, 0.f, 0.f};

    int arow = row0 + lm;
    int arow_c = (arow < N_DST) ? arow : (N_DST - 1);
    const ushort* aptr0 = hdb    + (size_t)arow_c * IN_FEAT + lk;
    const ushort* aptr1 = neighb + (size_t)arow_c * IN_FEAT + lk;
    const ushort* wp    = Wb + (size_t)lm * 256 + lk;

#pragma unroll
    for (int ks = 0; ks < 8; ++ks) {
        int k0 = ks * 32;
        const ushort* ap = (ks < 4) ? (aptr0 + k0) : (aptr1 + (k0 - 128));
        short8 afrag = *(const short8*)ap;
#pragma unroll
        for (int nt = 0; nt < 8; ++nt) {
            short8 bfrag = *(const short8*)(wp + (size_t)(nt * 16) * 256 + k0);
            acc[nt] = __builtin_amdgcn_mfma_f32_16x16x32_bf16(
                afrag, bfrag, acc[nt], 0, 0, 0);
        }
    }

    int orow_base = row0 + (lane >> 4) * 4;
#pragma unroll
    for (int nt = 0; nt < 8; ++nt) {
        int col = nt * 16 + lm;
        float bias = b[col];
#pragma unroll
        for (int r = 0; r < 4; ++r) {
            int orow = orow_base + r;
            if (orow < N_DST)
                out[(size_t)orow * OUT_FEAT + col] = acc[nt][r] + bias;
        }
    }
}

extern "C" void kernel_launch(void* const* d_in, const int* in_sizes, int n_in,
                              void* d_out, int out_size, void* d_ws, size_t ws_size,
                              hipStream_t stream) {
    const float* h_s = (const float*)d_in[0];
    const float* h_d = (const float*)d_in[1];
    const int*   src = (const int*)d_in[2];
    const int*   dst = (const int*)d_in[3];
    const float* W   = (const float*)d_in[4];
    const float* b   = (const float*)d_in[5];
    float* out = (float*)d_out;

    // workspace layout (~28.5 MB)
    int* deg     = (int*)d_ws;                 // N_DST (hist, then cursor)
    int* offsets = deg + N_DST;                // N_DST+1
    int* perm    = offsets + (N_DST + 1);      // N_EDGES
    int* bsum    = perm + N_EDGES;             // NB
    int* boff    = bsum + NB;                  // NB
    int  ihead   = N_DST + (N_DST + 1) + N_EDGES + 2 * NB;
    ihead = (ihead + 3) & ~3;                  // 16 B align
    ushort* hsb_hdb = (ushort*)((int*)d_ws + ihead);        // N_SRC*128 bf16
    ushort* neighb  = hsb_hdb + (size_t)N_SRC * IN_FEAT;    // N_DST*128 bf16
    ushort* Wb      = neighb + (size_t)N_DST * IN_FEAT;     // 128*256 bf16

    hipMemsetAsync(deg, 0, N_DST * sizeof(int), stream);

    // CSR build + h_s conversion
    cvt_bf16_kernel<<<(N_SRC * IN_FEAT / 4) / 256, 256, 0, stream>>>(h_s, hsb_hdb);
    cvt_bf16_kernel<<<(OUT_FEAT * 2 * IN_FEAT / 4) / 256, 256, 0, stream>>>(W, Wb);
    hist_kernel<<<(N_EDGES + 255) / 256, 256, 0, stream>>>(dst, deg);
    blockreduce_kernel<<<NB, 256, 0, stream>>>(deg, bsum);
    scanb_kernel<<<1, 256, 0, stream>>>(bsum, boff, offsets);
    scanc_kernel<<<NB, 256, 0, stream>>>(deg, boff, offsets);
    fill_kernel<<<(N_EDGES + 255) / 256, 256, 0, stream>>>(src, dst, deg, perm);

    // gather (reads hsb) ...
    gather_kernel<<<(N_DST + 3) / 4, 256, 0, stream>>>(
        hsb_hdb, offsets, perm, neighb);

    // ... then reuse the same buffer for bf16(h_d) (stream-ordered, safe)
    cvt_bf16_kernel<<<(N_DST * IN_FEAT / 4) / 256, 256, 0, stream>>>(h_d, hsb_hdb);

    gemm_mfma_kernel<<<(N_DST + 63) / 64, 256, 0, stream>>>(
        hsb_hdb, neighb, Wb, b, out);
}

// Round 7
// 219.353 us; speedup vs baseline: 3.4086x; 1.1105x over previous
//
#include <hip/hip_runtime.h>
#include <hip/hip_bf16.h>

#define N_SRC 50000
#define N_DST 50000
#define N_EDGES 600000
#define IN_FEAT 128
#define OUT_FEAT 128
#define NB 196   // ceil(N_DST/256)

typedef __attribute__((ext_vector_type(8))) short short8;   // 8 bf16 = 4 VGPRs
typedef __attribute__((ext_vector_type(4))) float float4v;  // MFMA C/D

#define HS4 (N_SRC * IN_FEAT / 4)          // 1,600,000 float4s
#define HD4 (N_DST * IN_FEAT / 4)          // 1,600,000
#define W4  (OUT_FEAT * 2 * IN_FEAT / 4)   // 8,192
#define CVT_TOTAL (HS4 + HD4 + W4)

// ---------------------------------------------------------------------------
// K0: fused f32->bf16 conversion for h_s, h_d, W (one launch)
// ---------------------------------------------------------------------------
__global__ __launch_bounds__(256) void cvt_all_kernel(
    const float* __restrict__ h_s, const float* __restrict__ h_d,
    const float* __restrict__ W, ushort* __restrict__ hsb,
    ushort* __restrict__ hdb, ushort* __restrict__ Wbg)
{
    int idx = blockIdx.x * 256 + threadIdx.x;
    if (idx >= CVT_TOTAL) return;
    const float* in;
    ushort* outp;
    int off;
    if (idx < HS4)            { in = h_s; outp = hsb; off = idx; }
    else if (idx < HS4 + HD4) { in = h_d; outp = hdb; off = idx - HS4; }
    else                      { in = W;   outp = Wbg; off = idx - HS4 - HD4; }
    float4 v = ((const float4*)in)[off];
    __hip_bfloat16 o[4];
    o[0] = __float2bfloat16(v.x);
    o[1] = __float2bfloat16(v.y);
    o[2] = __float2bfloat16(v.z);
    o[3] = __float2bfloat16(v.w);
    *(ushort4*)(outp + (size_t)off * 4) = *(ushort4*)o;
}

// ---------------------------------------------------------------------------
// K1: degree histogram
// ---------------------------------------------------------------------------
__global__ __launch_bounds__(256) void hist_kernel(
    const int* __restrict__ dst, int* __restrict__ deg)
{
    int e = blockIdx.x * 256 + threadIdx.x;
    if (e < N_EDGES) atomicAdd(&deg[dst[e]], 1);
}

// ---------------------------------------------------------------------------
// K2a/b/c: hierarchical exclusive scan of deg -> offsets + cursor
// ---------------------------------------------------------------------------
__global__ __launch_bounds__(256) void blockreduce_kernel(
    const int* __restrict__ deg, int* __restrict__ bsum)
{
    __shared__ int sh[256];
    int i = blockIdx.x * 256 + threadIdx.x;
    sh[threadIdx.x] = (i < N_DST) ? deg[i] : 0;
    __syncthreads();
#pragma unroll
    for (int o = 128; o > 0; o >>= 1) {
        if (threadIdx.x < o) sh[threadIdx.x] += sh[threadIdx.x + o];
        __syncthreads();
    }
    if (threadIdx.x == 0) bsum[blockIdx.x] = sh[0];
}

__global__ __launch_bounds__(256) void scanb_kernel(
    const int* __restrict__ bsum, int* __restrict__ boff,
    int* __restrict__ offsets)
{
    __shared__ int sh[256];
    int t = threadIdx.x;
    int v = (t < NB) ? bsum[t] : 0;
    sh[t] = v;
    __syncthreads();
#pragma unroll
    for (int o = 1; o < 256; o <<= 1) {
        int u = (t >= o) ? sh[t - o] : 0;
        __syncthreads();
        sh[t] += u;
        __syncthreads();
    }
    if (t < NB) boff[t] = sh[t] - v;
    if (t == 255) offsets[N_DST] = sh[255];
}

__global__ __launch_bounds__(256) void scanc_kernel(
    int* __restrict__ deg, const int* __restrict__ boff,
    int* __restrict__ offsets)
{
    __shared__ int sh[256];
    int i = blockIdx.x * 256 + threadIdx.x;
    int t = threadIdx.x;
    int v = (i < N_DST) ? deg[i] : 0;
    sh[t] = v;
    __syncthreads();
#pragma unroll
    for (int o = 1; o < 256; o <<= 1) {
        int u = (t >= o) ? sh[t - o] : 0;
        __syncthreads();
        sh[t] += u;
        __syncthreads();
    }
    int excl = sh[t] - v + boff[blockIdx.x];
    if (i < N_DST) {
        offsets[i] = excl;
        deg[i]     = excl;   // fill cursor
    }
}

// ---------------------------------------------------------------------------
// K3: fill edge permutation
// ---------------------------------------------------------------------------
__global__ __launch_bounds__(256) void fill_kernel(
    const int* __restrict__ src, const int* __restrict__ dst,
    int* __restrict__ cursor, int* __restrict__ perm)
{
    int e = blockIdx.x * 256 + threadIdx.x;
    if (e < N_EDGES) {
        int d = dst[e];
        int p = atomicAdd(&cursor[d], 1);
        perm[p] = src[e];
    }
}

// ---------------------------------------------------------------------------
// K4: gather-mean, one wave per dst row, bf16 in -> f32 acc -> bf16 out.
// ---------------------------------------------------------------------------
__global__ __launch_bounds__(256) void gather_kernel(
    const ushort* __restrict__ hsb, const int* __restrict__ offsets,
    const int* __restrict__ perm, ushort* __restrict__ neighb)
{
    int wave = threadIdx.x >> 6;
    int lane = threadIdx.x & 63;
    int row  = blockIdx.x * 4 + wave;
    if (row >= N_DST) return;

    int off = offsets[row];
    int end = offsets[row + 1];
    int dg  = end - off;

    float ax = 0.f, ay = 0.f;
    for (int j = off; j < end; j += 8) {
        int   s[8];
        float m[8];
        int s0 = perm[j];
#pragma unroll
        for (int q = 0; q < 8; ++q) {
            bool ok = (j + q < end);
            s[q] = ok ? perm[j + q] : s0;
            m[q] = ok ? 1.f : 0.f;
        }
        ushort2 u[8];
#pragma unroll
        for (int q = 0; q < 8; ++q)
            u[q] = ((const ushort2*)(hsb + (size_t)s[q] * IN_FEAT))[lane];
#pragma unroll
        for (int q = 0; q < 8; ++q) {
            ax += m[q] * __uint_as_float((unsigned)u[q].x << 16);
            ay += m[q] * __uint_as_float((unsigned)u[q].y << 16);
        }
    }
    float inv = (dg > 0) ? (1.0f / (float)dg) : 0.0f;
    __hip_bfloat16 ox = __float2bfloat16(ax * inv);
    __hip_bfloat16 oy = __float2bfloat16(ay * inv);
    ushort2 o = make_ushort2(*(ushort*)&ox, *(ushort*)&oy);
    ((ushort2*)(neighb + (size_t)row * IN_FEAT))[lane] = o;
}

// ---------------------------------------------------------------------------
// K5: MFMA bf16 GEMM with LDS-staged W: out = [hdb | neighb] @ W.T + b
// Block: 256 thr / 4 waves, 128 rows x 128 cols. Wave: 32 rows (2 m-frags).
// W staged fragment-major in LDS: frag f=(ks*8+nt), chunk (f*64+lane)*16 B
//   -> K-loop B-reads are lane-contiguous ds_read_b128, conflict-free.
// Per ks: 2 global A-loads + 8 ds_reads + 16 MFMAs (deep ILP vs R5's
// 64 scattered L2 loads / 64 MFMAs which was latency-serialized).
// ---------------------------------------------------------------------------
__global__ __launch_bounds__(256) void gemm_mfma_kernel(
    const ushort* __restrict__ hdb, const ushort* __restrict__ neighb,
    const ushort* __restrict__ Wbg, const float* __restrict__ b,
    float* __restrict__ out)
{
    __shared__ ushort sWb[64 * 64 * 8];   // 64 frags x 64 lanes x 8 bf16 = 64 KB

    int tid  = threadIdx.x;
    int wave = tid >> 6;
    int lane = tid & 63;
    int lm   = lane & 15;
    int lk   = (lane >> 4) * 8;

    // ---- stage W into LDS, fragment-major (16 x 16B per thread) ----
#pragma unroll
    for (int i = 0; i < 16; ++i) {
        int c  = i * 256 + tid;        // 0..4095 chunk id
        int f  = c >> 6;
        int l  = c & 63;
        int ks = f >> 3;
        int nt = f & 7;
        int row = nt * 16 + (l & 15);
        int col = ks * 32 + (l >> 4) * 8;
        short8 v = *(const short8*)(Wbg + (size_t)row * 256 + col);
        *(short8*)(sWb + (size_t)c * 8) = v;
    }
    __syncthreads();

    int row0 = blockIdx.x * 128 + wave * 32;

    float4v acc0[8], acc1[8];
#pragma unroll
    for (int nt = 0; nt < 8; ++nt) {
        acc0[nt] = (float4v){0.f, 0.f, 0.f, 0.f};
        acc1[nt] = (float4v){0.f, 0.f, 0.f, 0.f};
    }

    int ar0 = row0 + lm;       ar0 = (ar0 < N_DST) ? ar0 : (N_DST - 1);
    int ar1 = row0 + 16 + lm;  ar1 = (ar1 < N_DST) ? ar1 : (N_DST - 1);
    const ushort* a0d = hdb    + (size_t)ar0 * IN_FEAT + lk;
    const ushort* a1d = hdb    + (size_t)ar1 * IN_FEAT + lk;
    const ushort* a0n = neighb + (size_t)ar0 * IN_FEAT + lk;
    const ushort* a1n = neighb + (size_t)ar1 * IN_FEAT + lk;

#pragma unroll
    for (int ks = 0; ks < 8; ++ks) {
        int koff = (ks & 3) * 32;
        short8 af0 = (ks < 4) ? *(const short8*)(a0d + koff)
                              : *(const short8*)(a0n + koff);
        short8 af1 = (ks < 4) ? *(const short8*)(a1d + koff)
                              : *(const short8*)(a1n + koff);
#pragma unroll
        for (int nt = 0; nt < 8; ++nt) {
            short8 bf = *(const short8*)(sWb + ((size_t)(ks * 8 + nt) * 64 + lane) * 8);
            acc0[nt] = __builtin_amdgcn_mfma_f32_16x16x32_bf16(af0, bf, acc0[nt], 0, 0, 0);
            acc1[nt] = __builtin_amdgcn_mfma_f32_16x16x32_bf16(af1, bf, acc1[nt], 0, 0, 0);
        }
    }

    // ---- epilogue: C/D layout col=lane&15, row=(lane>>4)*4+reg ----
    int orow0 = row0 + (lane >> 4) * 4;
#pragma unroll
    for (int nt = 0; nt < 8; ++nt) {
        int col = nt * 16 + lm;
        float bias = b[col];
#pragma unroll
        for (int r = 0; r < 4; ++r) {
            int oa = orow0 + r;
            int ob = oa + 16;
            if (oa < N_DST) out[(size_t)oa * OUT_FEAT + col] = acc0[nt][r] + bias;
            if (ob < N_DST) out[(size_t)ob * OUT_FEAT + col] = acc1[nt][r] + bias;
        }
    }
}

extern "C" void kernel_launch(void* const* d_in, const int* in_sizes, int n_in,
                              void* d_out, int out_size, void* d_ws, size_t ws_size,
                              hipStream_t stream) {
    const float* h_s = (const float*)d_in[0];
    const float* h_d = (const float*)d_in[1];
    const int*   src = (const int*)d_in[2];
    const int*   dst = (const int*)d_in[3];
    const float* W   = (const float*)d_in[4];
    const float* b   = (const float*)d_in[5];
    float* out = (float*)d_out;

    // workspace layout (~41.5 MB; ws is >=256 MiB per harness poison size)
    int* deg     = (int*)d_ws;                 // N_DST (hist, then cursor)
    int* offsets = deg + N_DST;                // N_DST+1
    int* perm    = offsets + (N_DST + 1);      // N_EDGES
    int* bsum    = perm + N_EDGES;             // NB
    int* boff    = bsum + NB;                  // NB
    int  ihead   = N_DST + (N_DST + 1) + N_EDGES + 2 * NB;
    ihead = (ihead + 3) & ~3;                  // 16 B align
    ushort* hsb    = (ushort*)((int*)d_ws + ihead);       // N_SRC*128 bf16
    ushort* hdb    = hsb + (size_t)N_SRC * IN_FEAT;       // N_DST*128 bf16
    ushort* neighb = hdb + (size_t)N_DST * IN_FEAT;       // N_DST*128 bf16
    ushort* Wbg    = neighb + (size_t)N_DST * IN_FEAT;    // 128*256 bf16

    hipMemsetAsync(deg, 0, N_DST * sizeof(int), stream);

    cvt_all_kernel<<<(CVT_TOTAL + 255) / 256, 256, 0, stream>>>(
        h_s, h_d, W, hsb, hdb, Wbg);
    hist_kernel<<<(N_EDGES + 255) / 256, 256, 0, stream>>>(dst, deg);
    blockreduce_kernel<<<NB, 256, 0, stream>>>(deg, bsum);
    scanb_kernel<<<1, 256, 0, stream>>>(bsum, boff, offsets);
    scanc_kernel<<<NB, 256, 0, stream>>>(deg, boff, offsets);
    fill_kernel<<<(N_EDGES + 255) / 256, 256, 0, stream>>>(src, dst, deg, perm);
    gather_kernel<<<(N_DST + 3) / 4, 256, 0, stream>>>(
        hsb, offsets, perm, neighb);
    gemm_mfma_kernel<<<(N_DST + 127) / 128, 256, 0, stream>>>(
        hdb, neighb, Wbg, b, out);
}